// Round 6
// baseline (310.749 us; speedup 1.0000x reference)
//
#include <hip/hip_runtime.h>
#include <hip/hip_bf16.h>
#include <stdint.h>
#include <math.h>

#define SPB 32      // samples per main-kernel block
#define TT 8        // timesteps

typedef __attribute__((ext_vector_type(8))) short short8;  // bf16x8 MFMA frag
typedef __attribute__((ext_vector_type(4))) float f32x4;   // MFMA accumulator

__device__ __forceinline__ uint16_t bf16_rne(float f) {
  uint32_t u = __float_as_uint(f);
  return (uint16_t)((u + 0x7fffu + ((u >> 16) & 1u)) >> 16);
}
__device__ __forceinline__ float bf16_f32(uint16_t b) {
  return __uint_as_float((uint32_t)b << 16);
}

// --- threefry2x32, key schedule exactly as JAX (Random123) ---
__device__ __forceinline__ void threefry2x32(uint32_t k0, uint32_t k1,
                                             uint32_t x0, uint32_t x1,
                                             uint32_t& o0, uint32_t& o1) {
  const uint32_t ks2 = 0x1BD11BDAu ^ k0 ^ k1;
  uint32_t v0 = x0 + k0, v1 = x1 + k1;
#define TFR(r) { v0 += v1; v1 = (v1 << r) | (v1 >> (32 - r)); v1 ^= v0; }
  TFR(13) TFR(15) TFR(26) TFR(6)   v0 += k1;  v1 += ks2 + 1u;
  TFR(17) TFR(29) TFR(16) TFR(24)  v0 += ks2; v1 += k0 + 2u;
  TFR(13) TFR(15) TFR(26) TFR(6)   v0 += k0;  v1 += k1 + 3u;
  TFR(17) TFR(29) TFR(16) TFR(24)  v0 += k1;  v1 += ks2 + 4u;
  TFR(13) TFR(15) TFR(26) TFR(6)   v0 += ks2; v1 += k0 + 5u;
#undef TFR
  o0 = v0; o1 = v1;
}

// bernoulli(u < sigmoid(x)) with f32 fast path and exact f64 guard:
// |p32 - p64| <= ~2e-7 absolute; guard at 8e-6 -> decisions identical to
// pure-f64, guard path taken ~500x per launch device-wide.
__device__ __forceinline__ bool bern_lt(uint32_t bits, float p32, float xv) {
  const float u = __uint_as_float((bits >> 9) | 0x3f800000u) - 1.0f;
  const float d = u - p32;
  if (__builtin_expect(fabsf(d) < 8e-6f, 0)) {
    const double p = 1.0 / (1.0 + exp(-(double)xv));
    return (double)u < p;
  }
  return d < 0.0f;
}

// ---------------- encoder kernel (split mode) ----------------
// 2048 blocks x 256 thr; thread (b = tid>>4, w8 = tid&15) handles sample
// gb = blk*16+b, dims d in [w8*8, w8*8+8), all 8 t. Original JAX threefry
// stream: flat elem i<2^24 takes o0 of threefry(key,(i,i+2^24)), i>=2^24
// takes o1; per-t stride 2^22 pairs (t,b,d) with (t+4,b,d).
__global__ void __launch_bounds__(256)
enc_kernel(const float* __restrict__ x, uint32_t* __restrict__ s0g)
{
  __shared__ uint8_t sbits[128 * 16];   // [row = b*8+t][w8]
  const int tid = threadIdx.x;
  const int b = tid >> 4, w8 = tid & 15;
  const int gb = blockIdx.x * 16 + b;
  float xv[8];
  *(float4*)&xv[0] = *(const float4*)&x[(size_t)gb * 128 + w8 * 8];
  *(float4*)&xv[4] = *(const float4*)&x[(size_t)gb * 128 + w8 * 8 + 4];
  uint32_t m[TT] = {0, 0, 0, 0, 0, 0, 0, 0};
  #pragma unroll
  for (int j = 0; j < 8; ++j) {
    const int d = w8 * 8 + j;
    const float p32 = 1.0f / (1.0f + expf(-xv[j]));
    #pragma unroll
    for (int t = 0; t < 4; ++t) {
      const uint32_t e = ((uint32_t)t << 22) | ((uint32_t)gb << 7) | (uint32_t)d;
      uint32_t o0, o1;
      threefry2x32(0u, 42u, e, e + 0x01000000u, o0, o1);
      m[t]     |= (uint32_t)bern_lt(o0, p32, xv[j]) << j;
      m[t + 4] |= (uint32_t)bern_lt(o1, p32, xv[j]) << j;
    }
  }
  #pragma unroll
  for (int t = 0; t < TT; ++t)
    sbits[(b * 8 + t) * 16 + w8] = (uint8_t)m[t];
  __syncthreads();
  if (tid < 128)   // 128 rows x 16B, coalesced
    ((uint4*)s0g)[blockIdx.x * 128 + tid] = ((const uint4*)sbits)[tid];
}

// VALU Linear(+LIF) layer (layers 2..4); only called when msk != 0.
// WST=66 (float2-aligned); spikes bit-packed, s_out pre-zeroed; flg_next
// accumulates 64-neuron chunk occupancy.
template<int I, int O, bool LAST>
__device__ __forceinline__ void layer_valu(
    const float* __restrict__ Wg, const float* __restrict__ Bg,
    const uint32_t* __restrict__ s_in, uint8_t* __restrict__ s_out,
    uint32_t* __restrict__ flg_next,
    float* __restrict__ wbuf, float* __restrict__ bias_s,
    float* __restrict__ outp, int bglob0, uint32_t msk)
{
  constexpr int WST = 66;
  const int tid = threadIdx.x;
  const int b  = tid >> 3;  // 0..31
  const int oc = tid & 7;   // 0..7
  __syncthreads();
  if (tid < O) bias_s[tid] = Bg[tid];

  for (int q = 0; q < O / 64; ++q) {
    const int obase = q * 64;
    float acc[TT][8];
    #pragma unroll
    for (int t = 0; t < TT; ++t)
      #pragma unroll
      for (int j = 0; j < 8; ++j) acc[t][j] = 0.f;

    for (int ic = 0; ic < I / 64; ++ic) {
      if (!((msk >> ic) & 1u)) continue;
      __syncthreads();
      #pragma unroll
      for (int k = 0; k < 4; ++k) {
        int fi = tid + k * 256;
        int o  = fi >> 4;
        int i4 = fi & 15;
        const float4 w4 = *reinterpret_cast<const float4*>(
            &Wg[(size_t)(obase + o) * I + ic * 64 + i4 * 4]);
        float* wp = &wbuf[(i4 * 4) * WST + o];
        wp[0 * WST] = w4.x; wp[1 * WST] = w4.y;
        wp[2 * WST] = w4.z; wp[3 * WST] = w4.w;
      }
      __syncthreads();
      uint32_t r[TT][2];
      uint32_t any = 0;
      #pragma unroll
      for (int t = 0; t < TT; ++t) {
        const uint32_t* sp = &s_in[(size_t)(b * 8 + t) * (I / 32) + ic * 2];
        r[t][0] = sp[0]; r[t][1] = sp[1];
        any |= r[t][0] | r[t][1];
      }
      if (any) {
        #pragma unroll
        for (int w = 0; w < 2; ++w) {
          for (int i2 = 0; i2 < 32; ++i2) {
            const float* wrow = &wbuf[(w * 32 + i2) * WST + oc * 8];
            const float2 wa = *reinterpret_cast<const float2*>(wrow);
            const float2 wb = *reinterpret_cast<const float2*>(wrow + 2);
            const float2 wc = *reinterpret_cast<const float2*>(wrow + 4);
            const float2 wd = *reinterpret_cast<const float2*>(wrow + 6);
            #pragma unroll
            for (int t = 0; t < TT; ++t) {
              const float sf = (float)((r[t][w] >> i2) & 1u);
              acc[t][0] += wa.x * sf; acc[t][1] += wa.y * sf;
              acc[t][2] += wb.x * sf; acc[t][3] += wb.y * sf;
              acc[t][4] += wc.x * sf; acc[t][5] += wc.y * sf;
              acc[t][6] += wd.x * sf; acc[t][7] += wd.y * sf;
            }
          }
        }
      }
    }
    if constexpr (!LAST) {
      float v[8];
      #pragma unroll
      for (int j = 0; j < 8; ++j) v[j] = 0.f;
      #pragma unroll
      for (int t = 0; t < TT; ++t) {
        uint32_t m = 0;
        #pragma unroll
        for (int j = 0; j < 8; ++j) {
          const float cur = acc[t][j] + bias_s[obase + oc * 8 + j];
          const float vn = (v[j] + cur) * 0.5f;
          const bool s = vn >= 1.0f;
          m |= (uint32_t)s << j;
          v[j] = s ? 0.0f : vn;
        }
        if (m) {
          const int byi = (obase >> 3) + oc;
          s_out[(size_t)(b * 8 + t) * (O / 8) + byi] = (uint8_t)m;
          atomicOr(flg_next, 1u << (byi >> 3));
        }
      }
    } else {
      float oacc[8];
      #pragma unroll
      for (int j = 0; j < 8; ++j) oacc[j] = 0.f;
      #pragma unroll
      for (int t = 0; t < TT; ++t)
        #pragma unroll
        for (int j = 0; j < 8; ++j) oacc[j] += acc[t][j];
      float4 o0, o1;
      o0.x = oacc[0] * 0.125f + bias_s[oc * 8 + 0];
      o0.y = oacc[1] * 0.125f + bias_s[oc * 8 + 1];
      o0.z = oacc[2] * 0.125f + bias_s[oc * 8 + 2];
      o0.w = oacc[3] * 0.125f + bias_s[oc * 8 + 3];
      o1.x = oacc[4] * 0.125f + bias_s[oc * 8 + 4];
      o1.y = oacc[5] * 0.125f + bias_s[oc * 8 + 5];
      o1.z = oacc[6] * 0.125f + bias_s[oc * 8 + 6];
      o1.w = oacc[7] * 0.125f + bias_s[oc * 8 + 7];
      float* op = &outp[(size_t)(bglob0 + b) * 64 + oc * 8];
      *reinterpret_cast<float4*>(op)     = o0;
      *reinterpret_cast<float4*>(op + 4) = o1;
    }
  }
}

// LDS byte map (32272 B total):
//   [0,16896)       B_lds (L1 bf16 staging, 32 lines x 33 x 16B)
//                   / wbuf (L2-4 f32 staging, 64 x 66)
//   [16896,17920)   bias_s (256 f32)
//   [17920,22016)   s0 bits (fused-enc) -> reused as s2 after afrag build
//   [22016,30208)   s1 bits (256 rows x 32B)
//   [30208,32256)   s3 bits (256 rows x 8B)
//   [32256,32272)   flg[4]: s1/s2/s3 chunk-occupancy masks
template<bool FUSED_ENC>
__global__ void __launch_bounds__(256, 4)
snn_main(const float* __restrict__ x, const uint32_t* __restrict__ s0g,
         const float* __restrict__ W1, const float* __restrict__ B1,
         const float* __restrict__ W2, const float* __restrict__ B2,
         const float* __restrict__ W3, const float* __restrict__ B3,
         const float* __restrict__ W4, const float* __restrict__ B4,
         float* __restrict__ out)
{
  __shared__ __align__(16) uint8_t smem[32272];
  uint16_t* B_lds  = (uint16_t*)smem;
  float*    wbuf   = (float*)smem;
  float*    bias_s = (float*)(smem + 16896);
  uint32_t* s0     = (uint32_t*)(smem + 17920);
  uint8_t*  s2     = smem + 17920;
  uint16_t* s1     = (uint16_t*)(smem + 22016);
  uint8_t*  s3     = smem + 30208;
  uint32_t* flg    = (uint32_t*)(smem + 32256);

  const int tid = threadIdx.x;
  const int lane = tid & 63, wid = tid >> 6;
  const int bglob0 = blockIdx.x * SPB;

  // zero s1, s3, flg ([22016, 32272) = 2564 u32)
  for (int i = tid; i < 2564; i += 256)
    ((uint32_t*)(smem + 22016))[i] = 0;

  if constexpr (FUSED_ENC) {
    const int b = tid >> 3, w16 = tid & 7;
    const int gb = bglob0 + b;
    float xv[16];
    #pragma unroll
    for (int k = 0; k < 4; ++k)
      *(float4*)&xv[k * 4] =
          *(const float4*)&x[(size_t)gb * 128 + w16 * 16 + k * 4];
    uint32_t m[TT] = {0, 0, 0, 0, 0, 0, 0, 0};
    for (int j = 0; j < 16; ++j) {
      const int d = w16 * 16 + j;
      const float p32 = 1.0f / (1.0f + expf(-xv[j]));
      #pragma unroll
      for (int t = 0; t < 4; ++t) {
        const uint32_t e = ((uint32_t)t << 22) | ((uint32_t)gb << 7) | (uint32_t)d;
        uint32_t o0, o1;
        threefry2x32(0u, 42u, e, e + 0x01000000u, o0, o1);
        m[t]     |= (uint32_t)bern_lt(o0, p32, xv[j]) << j;
        m[t + 4] |= (uint32_t)bern_lt(o1, p32, xv[j]) << j;
      }
    }
    #pragma unroll
    for (int t = 0; t < TT; ++t)
      ((uint16_t*)s0)[(b * 8 + t) * 8 + w16] = (uint16_t)m[t];
  }
  bias_s[tid] = B1[tid];
  __syncthreads();

  // ---- Layer 1 MFMA: A-frags (spike bits -> bf16 {0,1}), built once ----
  short8 afrag[4][4];
  #pragma unroll
  for (int m = 0; m < 4; ++m) {
    const int row = wid * 64 + m * 16 + (lane & 15);
    #pragma unroll
    for (int s = 0; s < 4; ++s) {
      const uint32_t wrd = FUSED_ENC
          ? s0[row * 4 + s]
          : s0g[(size_t)blockIdx.x * 1024 + row * 4 + s];
      const uint32_t byte = (wrd >> ((lane >> 4) * 8)) & 0xffu;
      short8 a;
      #pragma unroll
      for (int j = 0; j < 8; ++j)
        a[j] = (short)(((byte >> j) & 1u) ? 0x3F80 : 0);
      afrag[m][s] = a;
    }
  }
  __syncthreads();            // all waves done with s0 region
  for (int i = tid; i < 1024; i += 256)   // zero s2 overlay (4KB)
    ((uint32_t*)s2)[i] = 0;

  for (int nc = 0; nc < 8; ++nc) {
    __syncthreads();          // prev nc's B_lds readers done (covers s2 zero)
    {   // stage W1 cols [nc*32,+32) as bf16 hi (sp 0..3) / lo (sp 4..7)
      const int col = tid >> 3, kq = tid & 7;
      const float* wsrc = &W1[(size_t)(nc * 32 + col) * 128 + kq * 16];
      float4 f[4];
      #pragma unroll
      for (int k = 0; k < 4; ++k)
        f[k] = *reinterpret_cast<const float4*>(wsrc + k * 4);
      #pragma unroll
      for (int h = 0; h < 2; ++h) {
        const int k0 = kq * 16 + h * 8;
        const int sp = k0 >> 5, g = (k0 >> 3) & 3;
        short8 hv, lv;
        #pragma unroll
        for (int e = 0; e < 8; ++e) {
          const float w = ((const float*)&f[2 * h])[e];
          const uint16_t hb = bf16_rne(w);
          const uint16_t lb = bf16_rne(w - bf16_f32(hb));
          hv[e] = (short)hb; lv[e] = (short)lb;
        }
        *(short8*)(B_lds + ((sp * 4 + g) * 33 + col) * 8)       = hv;
        *(short8*)(B_lds + (((sp + 4) * 4 + g) * 33 + col) * 8) = lv;
      }
    }
    __syncthreads();
    f32x4 C[4][2];
    #pragma unroll
    for (int m = 0; m < 4; ++m)
      #pragma unroll
      for (int nt = 0; nt < 2; ++nt)
        C[m][nt] = (f32x4){0.f, 0.f, 0.f, 0.f};
    #pragma unroll
    for (int nt = 0; nt < 2; ++nt)
      #pragma unroll
      for (int sp = 0; sp < 8; ++sp) {
        const short8 bf = *(const short8*)(
            B_lds + ((sp * 4 + (lane >> 4)) * 33 + nt * 16 + (lane & 15)) * 8);
        #pragma unroll
        for (int m = 0; m < 4; ++m)
          C[m][nt] = __builtin_amdgcn_mfma_f32_16x16x32_bf16(
              afrag[m][sp & 3], bf, C[m][nt], 0, 0, 0);
      }
    // gated LIF epilogue: spike needs current+bias > 1.0 (v<1 always),
    // so skip everything unless __any lane sees c >= 1.0.
    const int g = lane >> 4;
    #pragma unroll
    for (int m = 0; m < 4; ++m)
      #pragma unroll
      for (int nt = 0; nt < 2; ++nt) {
        const float bb = bias_s[nc * 32 + nt * 16 + (lane & 15)];
        const float c0 = C[m][nt][0] + bb, c1 = C[m][nt][1] + bb;
        const float c2 = C[m][nt][2] + bb, c3 = C[m][nt][3] + bb;
        const float mx = fmaxf(fmaxf(c0, c1), fmaxf(c2, c3));
        if (__any(mx >= 1.0f)) {
          float cr[4] = {c0, c1, c2, c3};
          float v = 0.f; uint32_t nib = 0;
          #pragma unroll
          for (int r = 0; r < 4; ++r) {
            const float vn = (v + cr[r]) * 0.5f;
            const bool s = vn >= 1.0f;
            nib |= (uint32_t)s << r;
            v = s ? 0.f : vn;
          }
          const float v3 = __shfl_xor(v, 16);
          if (g & 1) {   // upper-t lanes redo with true v after t=3
            v = v3; nib = 0;
            #pragma unroll
            for (int r = 0; r < 4; ++r) {
              const float vn = (v + cr[r]) * 0.5f;
              const bool s = vn >= 1.0f;
              nib |= (uint32_t)s << r;
              v = s ? 0.f : vn;
            }
          }
          #pragma unroll
          for (int r = 0; r < 4; ++r) {
            const unsigned long long bal = __ballot((nib >> r) & 1u);
            if ((lane & 15) == 0) {
              const uint16_t w16v = (uint16_t)((bal >> (g * 16)) & 0xffffu);
              if (w16v) {
                const int row = wid * 64 + m * 16 + g * 4 + r;
                const int wds = nc * 2 + nt;
                s1[row * 16 + wds] = w16v;
                atomicOr(&flg[0], 1u << (wds >> 2));
              }
            }
          }
        }
      }
  }

  // ---- Layers 2..4 (VALU, block-uniform silent skip) ----
  __syncthreads();
  const uint32_t m1 = flg[0];
  if (m1)
    layer_valu<256, 128, false>(W2, B2, (const uint32_t*)s1, s2, &flg[1],
                                wbuf, bias_s, nullptr, bglob0, m1);
  __syncthreads();
  const uint32_t m2 = flg[1];
  if (m2)
    layer_valu<128, 64, false>(W3, B3, (const uint32_t*)s2, s3, &flg[2],
                               wbuf, bias_s, nullptr, bglob0, m2);
  __syncthreads();
  const uint32_t m3 = flg[2];
  if (m3) {
    layer_valu<64, 64, true>(W4, B4, (const uint32_t*)s3, nullptr, nullptr,
                             wbuf, bias_s, out, bglob0, m3);
  } else {
    const int b = tid >> 3, oc = tid & 7;
    const float4 b0 = *reinterpret_cast<const float4*>(&B4[oc * 8]);
    const float4 b1 = *reinterpret_cast<const float4*>(&B4[oc * 8 + 4]);
    float* op = &out[(size_t)(bglob0 + b) * 64 + oc * 8];
    *reinterpret_cast<float4*>(op)     = b0;
    *reinterpret_cast<float4*>(op + 4) = b1;
  }
}

extern "C" void kernel_launch(void* const* d_in, const int* in_sizes, int n_in,
                              void* d_out, int out_size, void* d_ws, size_t ws_size,
                              hipStream_t stream) {
  const float* x  = (const float*)d_in[0];
  const float* W1 = (const float*)d_in[1];
  const float* B1 = (const float*)d_in[2];
  const float* W2 = (const float*)d_in[3];
  const float* B2 = (const float*)d_in[4];
  const float* W3 = (const float*)d_in[5];
  const float* B3 = (const float*)d_in[6];
  const float* W4 = (const float*)d_in[7];
  const float* B4 = (const float*)d_in[8];
  float* out = (float*)d_out;
  const size_t bits_bytes = (size_t)32768 * TT * 16;  // 4 MB
  if (ws_size >= bits_bytes) {
    uint32_t* s0g = (uint32_t*)d_ws;
    hipLaunchKernelGGL(enc_kernel, dim3(2048), dim3(256), 0, stream, x, s0g);
    hipLaunchKernelGGL(snn_main<false>, dim3(32768 / SPB), dim3(256), 0, stream,
                       x, s0g, W1, B1, W2, B2, W3, B3, W4, B4, out);
  } else {
    hipLaunchKernelGGL(snn_main<true>, dim3(32768 / SPB), dim3(256), 0, stream,
                       x, nullptr, W1, B1, W2, B2, W3, B3, W4, B4, out);
  }
}

// Round 7
// 294.572 us; speedup vs baseline: 1.0549x; 1.0549x over previous
//
#include <hip/hip_runtime.h>
#include <hip/hip_bf16.h>
#include <stdint.h>
#include <math.h>

#define TT 8

typedef __attribute__((ext_vector_type(8))) short short8;  // bf16x8 MFMA frag
typedef __attribute__((ext_vector_type(4))) float f32x4;   // MFMA accumulator

__device__ __forceinline__ uint16_t bf16_rne(float f) {
  uint32_t u = __float_as_uint(f);
  return (uint16_t)((u + 0x7fffu + ((u >> 16) & 1u)) >> 16);
}
__device__ __forceinline__ float bf16_f32(uint16_t b) {
  return __uint_as_float((uint32_t)b << 16);
}

// --- threefry2x32, key schedule exactly as JAX (Random123) ---
__device__ __forceinline__ void threefry2x32(uint32_t k0, uint32_t k1,
                                             uint32_t x0, uint32_t x1,
                                             uint32_t& o0, uint32_t& o1) {
  const uint32_t ks2 = 0x1BD11BDAu ^ k0 ^ k1;
  uint32_t v0 = x0 + k0, v1 = x1 + k1;
#define TFR(r) { v0 += v1; v1 = (v1 << r) | (v1 >> (32 - r)); v1 ^= v0; }
  TFR(13) TFR(15) TFR(26) TFR(6)   v0 += k1;  v1 += ks2 + 1u;
  TFR(17) TFR(29) TFR(16) TFR(24)  v0 += ks2; v1 += k0 + 2u;
  TFR(13) TFR(15) TFR(26) TFR(6)   v0 += k0;  v1 += k1 + 3u;
  TFR(17) TFR(29) TFR(16) TFR(24)  v0 += k1;  v1 += ks2 + 4u;
  TFR(13) TFR(15) TFR(26) TFR(6)   v0 += ks2; v1 += k0 + 5u;
#undef TFR
  o0 = v0; o1 = v1;
}

// bernoulli(u < sigmoid(x)): f32 fast path + exact f64 guard (~500 hits/launch)
__device__ __forceinline__ bool bern_lt(uint32_t bits, float p32, float xv) {
  const float u = __uint_as_float((bits >> 9) | 0x3f800000u) - 1.0f;
  const float d = u - p32;
  if (__builtin_expect(fabsf(d) < 8e-6f, 0)) {
    const double p = 1.0 / (1.0 + exp(-(double)xv));
    return (double)u < p;
  }
  return d < 0.0f;
}

// ---------------- encoder kernel ----------------
// Original JAX threefry stream: flat elem i<2^24 takes o0 of
// threefry(key,(i,i+2^24)), i>=2^24 takes o1; per-t stride 2^22 pairs
// (t,b,d) with (t+4,b,d).
__global__ void __launch_bounds__(256)
enc_kernel(const float* __restrict__ x, uint32_t* __restrict__ s0g)
{
  __shared__ uint8_t sbits[128 * 16];   // [row = b*8+t][w8]
  const int tid = threadIdx.x;
  const int b = tid >> 4, w8 = tid & 15;
  const int gb = blockIdx.x * 16 + b;
  float xv[8];
  *(float4*)&xv[0] = *(const float4*)&x[(size_t)gb * 128 + w8 * 8];
  *(float4*)&xv[4] = *(const float4*)&x[(size_t)gb * 128 + w8 * 8 + 4];
  uint32_t m[TT] = {0, 0, 0, 0, 0, 0, 0, 0};
  #pragma unroll
  for (int j = 0; j < 8; ++j) {
    const int d = w8 * 8 + j;
    const float p32 = 1.0f / (1.0f + expf(-xv[j]));
    #pragma unroll
    for (int t = 0; t < 4; ++t) {
      const uint32_t e = ((uint32_t)t << 22) | ((uint32_t)gb << 7) | (uint32_t)d;
      uint32_t o0, o1;
      threefry2x32(0u, 42u, e, e + 0x01000000u, o0, o1);
      m[t]     |= (uint32_t)bern_lt(o0, p32, xv[j]) << j;
      m[t + 4] |= (uint32_t)bern_lt(o1, p32, xv[j]) << j;
    }
  }
  #pragma unroll
  for (int t = 0; t < TT; ++t)
    sbits[(b * 8 + t) * 16 + w8] = (uint8_t)m[t];
  __syncthreads();
  if (tid < 128)
    ((uint4*)s0g)[blockIdx.x * 128 + tid] = ((const uint4*)sbits)[tid];
}

// ---------------- W1 -> bf16(hi) fragment-layout precompute ----------------
// W1s[(((nc*4+sp)*64+lane)*2+nt)*8+j] = bf16(W1[n][k]),
//   n = nc*32 + nt*16 + (lane&15), k = sp*32 + (lane>>4)*8 + j.
// Main kernel B-frag for (nc,sp,nt) = 16B at lane*32 + nt*16 (coalesced).
__global__ void __launch_bounds__(256)
w1split_kernel(const float* __restrict__ W1, uint16_t* __restrict__ W1s)
{
  const int gid = blockIdx.x * 256 + threadIdx.x;   // 32768
  const int j = gid & 7, nt = (gid >> 3) & 1, lane = (gid >> 4) & 63;
  const int sp = (gid >> 10) & 3, nc = gid >> 12;
  const int k = sp * 32 + (lane >> 4) * 8 + j;
  const int n = nc * 32 + nt * 16 + (lane & 15);
  W1s[gid] = bf16_rne(W1[n * 128 + k]);
}

// ---------------- VALU Linear(+LIF) layers 2..4 ----------------
template<int I, int O, bool LAST>
__device__ __forceinline__ void layer_valu(
    const float* __restrict__ Wg, const float* __restrict__ Bg,
    const uint32_t* __restrict__ s_in, uint8_t* __restrict__ s_out,
    uint32_t* __restrict__ flg_next,
    float* __restrict__ wbuf, float* __restrict__ bias_s,
    float* __restrict__ outp, int bglob0, uint32_t msk)
{
  constexpr int WST = 66;
  const int tid = threadIdx.x;
  const int b  = tid >> 3;  // 0..31
  const int oc = tid & 7;   // 0..7
  __syncthreads();
  if (tid < O) bias_s[tid] = Bg[tid];

  for (int q = 0; q < O / 64; ++q) {
    const int obase = q * 64;
    float acc[TT][8];
    #pragma unroll
    for (int t = 0; t < TT; ++t)
      #pragma unroll
      for (int j = 0; j < 8; ++j) acc[t][j] = 0.f;

    for (int ic = 0; ic < I / 64; ++ic) {
      if (!((msk >> ic) & 1u)) continue;
      __syncthreads();
      #pragma unroll
      for (int k = 0; k < 4; ++k) {
        int fi = tid + k * 256;
        int o  = fi >> 4;
        int i4 = fi & 15;
        const float4 w4 = *reinterpret_cast<const float4*>(
            &Wg[(size_t)(obase + o) * I + ic * 64 + i4 * 4]);
        float* wp = &wbuf[(i4 * 4) * WST + o];
        wp[0 * WST] = w4.x; wp[1 * WST] = w4.y;
        wp[2 * WST] = w4.z; wp[3 * WST] = w4.w;
      }
      __syncthreads();
      uint32_t r[TT][2];
      uint32_t any = 0;
      #pragma unroll
      for (int t = 0; t < TT; ++t) {
        const uint32_t* sp = &s_in[(size_t)(b * 8 + t) * (I / 32) + ic * 2];
        r[t][0] = sp[0]; r[t][1] = sp[1];
        any |= r[t][0] | r[t][1];
      }
      if (any) {
        #pragma unroll
        for (int w = 0; w < 2; ++w) {
          for (int i2 = 0; i2 < 32; ++i2) {
            const float* wrow = &wbuf[(w * 32 + i2) * WST + oc * 8];
            const float2 wa = *reinterpret_cast<const float2*>(wrow);
            const float2 wb = *reinterpret_cast<const float2*>(wrow + 2);
            const float2 wc = *reinterpret_cast<const float2*>(wrow + 4);
            const float2 wd = *reinterpret_cast<const float2*>(wrow + 6);
            #pragma unroll
            for (int t = 0; t < TT; ++t) {
              const float sf = (float)((r[t][w] >> i2) & 1u);
              acc[t][0] += wa.x * sf; acc[t][1] += wa.y * sf;
              acc[t][2] += wb.x * sf; acc[t][3] += wb.y * sf;
              acc[t][4] += wc.x * sf; acc[t][5] += wc.y * sf;
              acc[t][6] += wd.x * sf; acc[t][7] += wd.y * sf;
            }
          }
        }
      }
    }
    if constexpr (!LAST) {
      float v[8];
      #pragma unroll
      for (int j = 0; j < 8; ++j) v[j] = 0.f;
      #pragma unroll
      for (int t = 0; t < TT; ++t) {
        uint32_t m = 0;
        #pragma unroll
        for (int j = 0; j < 8; ++j) {
          const float cur = acc[t][j] + bias_s[obase + oc * 8 + j];
          const float vn = (v[j] + cur) * 0.5f;
          const bool s = vn >= 1.0f;
          m |= (uint32_t)s << j;
          v[j] = s ? 0.0f : vn;
        }
        if (m) {
          const int byi = (obase >> 3) + oc;
          s_out[(size_t)(b * 8 + t) * (O / 8) + byi] = (uint8_t)m;
          atomicOr(flg_next, 1u << (byi >> 3));
        }
      }
    } else {
      float oacc[8];
      #pragma unroll
      for (int j = 0; j < 8; ++j) oacc[j] = 0.f;
      #pragma unroll
      for (int t = 0; t < TT; ++t)
        #pragma unroll
        for (int j = 0; j < 8; ++j) oacc[j] += acc[t][j];
      float4 o0, o1;
      o0.x = oacc[0] * 0.125f + bias_s[oc * 8 + 0];
      o0.y = oacc[1] * 0.125f + bias_s[oc * 8 + 1];
      o0.z = oacc[2] * 0.125f + bias_s[oc * 8 + 2];
      o0.w = oacc[3] * 0.125f + bias_s[oc * 8 + 3];
      o1.x = oacc[4] * 0.125f + bias_s[oc * 8 + 4];
      o1.y = oacc[5] * 0.125f + bias_s[oc * 8 + 5];
      o1.z = oacc[6] * 0.125f + bias_s[oc * 8 + 6];
      o1.w = oacc[7] * 0.125f + bias_s[oc * 8 + 7];
      float* op = &outp[(size_t)(bglob0 + b) * 64 + oc * 8];
      *reinterpret_cast<float4*>(op)     = o0;
      *reinterpret_cast<float4*>(op + 4) = o1;
    }
  }
}

// LDS byte map (32272 B):
//   [0,16896)       wbuf (L2-4 f32 staging, 64 x 66)
//   [16896,17920)   bias_s (256 f32)
//   [17920,22016)   s2 bits
//   [22016,30208)   s1 bits (256 rows x 32B)
//   [30208,32256)   s3 bits
//   [32256,32272)   flg[4]
__global__ void __launch_bounds__(256, 4)
snn_main_split(const uint32_t* __restrict__ s0g, const uint16_t* __restrict__ W1s,
               const float* __restrict__ B1,
               const float* __restrict__ W2, const float* __restrict__ B2,
               const float* __restrict__ W3, const float* __restrict__ B3,
               const float* __restrict__ W4, const float* __restrict__ B4,
               float* __restrict__ out)
{
  __shared__ __align__(16) uint8_t smem[32272];
  float*    wbuf   = (float*)smem;
  float*    bias_s = (float*)(smem + 16896);
  uint8_t*  s2     = smem + 17920;
  uint16_t* s1     = (uint16_t*)(smem + 22016);
  uint8_t*  s3     = smem + 30208;
  uint32_t* flg    = (uint32_t*)(smem + 32256);

  const int tid = threadIdx.x;
  const int lane = tid & 63, wid = tid >> 6;
  const int g = lane >> 4;
  const int bglob0 = blockIdx.x * 32;

  for (int i = tid; i < 3588; i += 256)   // zero s2,s1,s3,flg
    ((uint32_t*)(smem + 17920))[i] = 0;
  bias_s[tid] = B1[tid];
  __syncthreads();

  const uint8_t* wlane = (const uint8_t*)W1s + lane * 32;

  #pragma unroll 1
  for (int half = 0; half < 2; ++half) {
    // A-frags (spike bits -> bf16 {0,1}) for this half's 2 M-tiles
    short8 afrag[2][4];
    #pragma unroll
    for (int mi = 0; mi < 2; ++mi) {
      const int row = wid * 64 + (half * 2 + mi) * 16 + (lane & 15);
      const uint4 w4 = ((const uint4*)s0g)[blockIdx.x * 256 + row];
      const uint32_t ws[4] = {w4.x, w4.y, w4.z, w4.w};
      #pragma unroll
      for (int s = 0; s < 4; ++s) {
        const uint32_t byte = (ws[s] >> (g * 8)) & 0xffu;
        short8 a;
        #pragma unroll
        for (int j = 0; j < 8; ++j)
          a[j] = (short)(((byte >> j) & 1u) ? 0x3F80 : 0);
        afrag[mi][s] = a;
      }
    }

    #pragma unroll 1
    for (int nc = 0; nc < 8; ++nc) {
      const uint8_t* wnc = wlane + nc * 8192;
      f32x4 C[2][2];
      #pragma unroll
      for (int mi = 0; mi < 2; ++mi)
        #pragma unroll
        for (int nt = 0; nt < 2; ++nt)
          C[mi][nt] = (f32x4){0.f, 0.f, 0.f, 0.f};

      short8 bb_[2][2];   // double-buffered B frags, static-indexed via unroll
      bb_[0][0] = *(const short8*)(wnc);
      bb_[0][1] = *(const short8*)(wnc + 16);
      #pragma unroll
      for (int sp = 0; sp < 4; ++sp) {
        if (sp < 3) {
          bb_[(sp + 1) & 1][0] = *(const short8*)(wnc + (sp + 1) * 2048);
          bb_[(sp + 1) & 1][1] = *(const short8*)(wnc + (sp + 1) * 2048 + 16);
        }
        #pragma unroll
        for (int nt = 0; nt < 2; ++nt)
          #pragma unroll
          for (int mi = 0; mi < 2; ++mi)
            C[mi][nt] = __builtin_amdgcn_mfma_f32_16x16x32_bf16(
                afrag[mi][sp], bb_[sp & 1][nt], C[mi][nt], 0, 0, 0);
      }

      // Epilogue. Exact gate via no-reset envelope u: v_t <= u_t always
      // (reset only lowers v; u >= 1 at any spike), so max u < 1 => silent.
      // Upper-half lanes bound true u by pu + max(u3_low,0)/2.
      #pragma unroll
      for (int mi = 0; mi < 2; ++mi)
        #pragma unroll
        for (int nt = 0; nt < 2; ++nt) {
          const float bbv = bias_s[nc * 32 + nt * 16 + (lane & 15)];
          float cr[4];
          #pragma unroll
          for (int r = 0; r < 4; ++r) cr[r] = C[mi][nt][r] + bbv;
          float u = cr[0] * 0.5f;
          float mx = u;
          u = (u + cr[1]) * 0.5f; mx = fmaxf(mx, u);
          u = (u + cr[2]) * 0.5f; mx = fmaxf(mx, u);
          u = (u + cr[3]) * 0.5f; mx = fmaxf(mx, u);
          const float u3o = __shfl_xor(u, 16);
          const float ub = (g & 1) ? mx + fmaxf(u3o, 0.f) * 0.5f : mx;
          if (__any(ub >= 1.0f)) {
            float v = 0.f; uint32_t nib = 0;
            #pragma unroll
            for (int r = 0; r < 4; ++r) {
              const float vn = (v + cr[r]) * 0.5f;
              const bool s = vn >= 1.0f;
              nib |= (uint32_t)s << r;
              v = s ? 0.f : vn;
            }
            const float v3 = __shfl_xor(v, 16);
            if (g & 1) {   // upper-t lanes redo with true seed
              v = v3; nib = 0;
              #pragma unroll
              for (int r = 0; r < 4; ++r) {
                const float vn = (v + cr[r]) * 0.5f;
                const bool s = vn >= 1.0f;
                nib |= (uint32_t)s << r;
                v = s ? 0.f : vn;
              }
            }
            #pragma unroll
            for (int r = 0; r < 4; ++r) {
              const unsigned long long bal = __ballot((nib >> r) & 1u);
              if ((lane & 15) == 0) {
                const uint16_t w16v = (uint16_t)((bal >> (g * 16)) & 0xffffu);
                if (w16v) {
                  const int row = wid * 64 + (half * 2 + mi) * 16 + g * 4 + r;
                  const int wds = nc * 2 + nt;
                  s1[row * 16 + wds] = w16v;
                  atomicOr(&flg[0], 1u << (wds >> 2));
                }
              }
            }
          }
        }
    }
  }

  // ---- Layers 2..4 (VALU, block-uniform silent skip) ----
  __syncthreads();
  const uint32_t m1 = flg[0];
  if (m1)
    layer_valu<256, 128, false>(W2, B2, (const uint32_t*)s1, s2, &flg[1],
                                wbuf, bias_s, nullptr, bglob0, m1);
  __syncthreads();
  const uint32_t m2 = flg[1];
  if (m2)
    layer_valu<128, 64, false>(W3, B3, (const uint32_t*)s2, s3, &flg[2],
                               wbuf, bias_s, nullptr, bglob0, m2);
  __syncthreads();
  const uint32_t m3 = flg[2];
  if (m3) {
    layer_valu<64, 64, true>(W4, B4, (const uint32_t*)s3, nullptr, nullptr,
                             wbuf, bias_s, out, bglob0, m3);
  } else {
    const int b = tid >> 3, oc = tid & 7;
    const float4 b0 = *reinterpret_cast<const float4*>(&B4[oc * 8]);
    const float4 b1 = *reinterpret_cast<const float4*>(&B4[oc * 8 + 4]);
    float* op = &out[(size_t)(bglob0 + b) * 64 + oc * 8];
    *reinterpret_cast<float4*>(op)     = b0;
    *reinterpret_cast<float4*>(op + 4) = b1;
  }
}

// ---------------- fused fallback (round-6 verified path) ----------------
__global__ void __launch_bounds__(256, 4)
snn_fb(const float* __restrict__ x,
       const float* __restrict__ W1, const float* __restrict__ B1,
       const float* __restrict__ W2, const float* __restrict__ B2,
       const float* __restrict__ W3, const float* __restrict__ B3,
       const float* __restrict__ W4, const float* __restrict__ B4,
       float* __restrict__ out)
{
  __shared__ __align__(16) uint8_t smem[32272];
  uint16_t* B_lds  = (uint16_t*)smem;
  float*    wbuf   = (float*)smem;
  float*    bias_s = (float*)(smem + 16896);
  uint32_t* s0     = (uint32_t*)(smem + 17920);
  uint8_t*  s2     = smem + 17920;
  uint16_t* s1     = (uint16_t*)(smem + 22016);
  uint8_t*  s3     = smem + 30208;
  uint32_t* flg    = (uint32_t*)(smem + 32256);

  const int tid = threadIdx.x;
  const int lane = tid & 63, wid = tid >> 6;
  const int bglob0 = blockIdx.x * 32;

  for (int i = tid; i < 2564; i += 256)
    ((uint32_t*)(smem + 22016))[i] = 0;

  {
    const int b = tid >> 3, w16 = tid & 7;
    const int gb = bglob0 + b;
    float xv[16];
    #pragma unroll
    for (int k = 0; k < 4; ++k)
      *(float4*)&xv[k * 4] =
          *(const float4*)&x[(size_t)gb * 128 + w16 * 16 + k * 4];
    uint32_t m[TT] = {0, 0, 0, 0, 0, 0, 0, 0};
    for (int j = 0; j < 16; ++j) {
      const int d = w16 * 16 + j;
      const float p32 = 1.0f / (1.0f + expf(-xv[j]));
      #pragma unroll
      for (int t = 0; t < 4; ++t) {
        const uint32_t e = ((uint32_t)t << 22) | ((uint32_t)gb << 7) | (uint32_t)d;
        uint32_t o0, o1;
        threefry2x32(0u, 42u, e, e + 0x01000000u, o0, o1);
        m[t]     |= (uint32_t)bern_lt(o0, p32, xv[j]) << j;
        m[t + 4] |= (uint32_t)bern_lt(o1, p32, xv[j]) << j;
      }
    }
    #pragma unroll
    for (int t = 0; t < TT; ++t)
      ((uint16_t*)s0)[(b * 8 + t) * 8 + w16] = (uint16_t)m[t];
  }
  bias_s[tid] = B1[tid];
  __syncthreads();

  short8 afrag[4][4];
  #pragma unroll
  for (int m = 0; m < 4; ++m) {
    const int row = wid * 64 + m * 16 + (lane & 15);
    #pragma unroll
    for (int s = 0; s < 4; ++s) {
      const uint32_t wrd = s0[row * 4 + s];
      const uint32_t byte = (wrd >> ((lane >> 4) * 8)) & 0xffu;
      short8 a;
      #pragma unroll
      for (int j = 0; j < 8; ++j)
        a[j] = (short)(((byte >> j) & 1u) ? 0x3F80 : 0);
      afrag[m][s] = a;
    }
  }
  __syncthreads();
  for (int i = tid; i < 1024; i += 256)
    ((uint32_t*)s2)[i] = 0;

  for (int nc = 0; nc < 8; ++nc) {
    __syncthreads();
    {
      const int col = tid >> 3, kq = tid & 7;
      const float* wsrc = &W1[(size_t)(nc * 32 + col) * 128 + kq * 16];
      float4 f[4];
      #pragma unroll
      for (int k = 0; k < 4; ++k)
        f[k] = *reinterpret_cast<const float4*>(wsrc + k * 4);
      #pragma unroll
      for (int h = 0; h < 2; ++h) {
        const int k0 = kq * 16 + h * 8;
        const int sp = k0 >> 5, gg = (k0 >> 3) & 3;
        short8 hv, lv;
        #pragma unroll
        for (int e = 0; e < 8; ++e) {
          const float w = ((const float*)&f[2 * h])[e];
          const uint16_t hb = bf16_rne(w);
          const uint16_t lb = bf16_rne(w - bf16_f32(hb));
          hv[e] = (short)hb; lv[e] = (short)lb;
        }
        *(short8*)(B_lds + ((sp * 4 + gg) * 33 + col) * 8)       = hv;
        *(short8*)(B_lds + (((sp + 4) * 4 + gg) * 33 + col) * 8) = lv;
      }
    }
    __syncthreads();
    f32x4 C[4][2];
    #pragma unroll
    for (int m = 0; m < 4; ++m)
      #pragma unroll
      for (int nt = 0; nt < 2; ++nt)
        C[m][nt] = (f32x4){0.f, 0.f, 0.f, 0.f};
    #pragma unroll
    for (int nt = 0; nt < 2; ++nt)
      #pragma unroll
      for (int sp = 0; sp < 8; ++sp) {
        const short8 bf = *(const short8*)(
            B_lds + ((sp * 4 + (lane >> 4)) * 33 + nt * 16 + (lane & 15)) * 8);
        #pragma unroll
        for (int m = 0; m < 4; ++m)
          C[m][nt] = __builtin_amdgcn_mfma_f32_16x16x32_bf16(
              afrag[m][sp & 3], bf, C[m][nt], 0, 0, 0);
      }
    const int g = lane >> 4;
    #pragma unroll
    for (int m = 0; m < 4; ++m)
      #pragma unroll
      for (int nt = 0; nt < 2; ++nt) {
        const float bb = bias_s[nc * 32 + nt * 16 + (lane & 15)];
        const float c0 = C[m][nt][0] + bb, c1 = C[m][nt][1] + bb;
        const float c2 = C[m][nt][2] + bb, c3 = C[m][nt][3] + bb;
        const float mxc = fmaxf(fmaxf(c0, c1), fmaxf(c2, c3));
        if (__any(mxc >= 1.0f)) {
          float cr[4] = {c0, c1, c2, c3};
          float v = 0.f; uint32_t nib = 0;
          #pragma unroll
          for (int r = 0; r < 4; ++r) {
            const float vn = (v + cr[r]) * 0.5f;
            const bool s = vn >= 1.0f;
            nib |= (uint32_t)s << r;
            v = s ? 0.f : vn;
          }
          const float v3 = __shfl_xor(v, 16);
          if (g & 1) {
            v = v3; nib = 0;
            #pragma unroll
            for (int r = 0; r < 4; ++r) {
              const float vn = (v + cr[r]) * 0.5f;
              const bool s = vn >= 1.0f;
              nib |= (uint32_t)s << r;
              v = s ? 0.f : vn;
            }
          }
          #pragma unroll
          for (int r = 0; r < 4; ++r) {
            const unsigned long long bal = __ballot((nib >> r) & 1u);
            if ((lane & 15) == 0) {
              const uint16_t w16v = (uint16_t)((bal >> (g * 16)) & 0xffffu);
              if (w16v) {
                const int row = wid * 64 + m * 16 + g * 4 + r;
                const int wds = nc * 2 + nt;
                s1[row * 16 + wds] = w16v;
                atomicOr(&flg[0], 1u << (wds >> 2));
              }
            }
          }
        }
      }
  }

  __syncthreads();
  const uint32_t m1 = flg[0];
  if (m1)
    layer_valu<256, 128, false>(W2, B2, (const uint32_t*)s1, s2, &flg[1],
                                wbuf, bias_s, nullptr, bglob0, m1);
  __syncthreads();
  const uint32_t m2 = flg[1];
  if (m2)
    layer_valu<128, 64, false>(W3, B3, (const uint32_t*)s2, s3, &flg[2],
                               wbuf, bias_s, nullptr, bglob0, m2);
  __syncthreads();
  const uint32_t m3 = flg[2];
  if (m3) {
    layer_valu<64, 64, true>(W4, B4, (const uint32_t*)s3, nullptr, nullptr,
                             wbuf, bias_s, out, bglob0, m3);
  } else {
    const int b = tid >> 3, oc = tid & 7;
    const float4 b0 = *reinterpret_cast<const float4*>(&B4[oc * 8]);
    const float4 b1 = *reinterpret_cast<const float4*>(&B4[oc * 8 + 4]);
    float* op = &out[(size_t)(bglob0 + b) * 64 + oc * 8];
    *reinterpret_cast<float4*>(op)     = b0;
    *reinterpret_cast<float4*>(op + 4) = b1;
  }
}

extern "C" void kernel_launch(void* const* d_in, const int* in_sizes, int n_in,
                              void* d_out, int out_size, void* d_ws, size_t ws_size,
                              hipStream_t stream) {
  const float* x  = (const float*)d_in[0];
  const float* W1 = (const float*)d_in[1];
  const float* B1 = (const float*)d_in[2];
  const float* W2 = (const float*)d_in[3];
  const float* B2 = (const float*)d_in[4];
  const float* W3 = (const float*)d_in[5];
  const float* B3 = (const float*)d_in[6];
  const float* W4 = (const float*)d_in[7];
  const float* B4 = (const float*)d_in[8];
  float* out = (float*)d_out;
  const size_t bits_bytes = (size_t)32768 * TT * 16;        // 4 MB
  const size_t w1s_bytes  = 32768 * sizeof(uint16_t);       // 64 KB
  if (ws_size >= bits_bytes + w1s_bytes) {
    uint32_t* s0g = (uint32_t*)d_ws;
    uint16_t* W1s = (uint16_t*)((uint8_t*)d_ws + bits_bytes);
    hipLaunchKernelGGL(enc_kernel, dim3(2048), dim3(256), 0, stream, x, s0g);
    hipLaunchKernelGGL(w1split_kernel, dim3(128), dim3(256), 0, stream, W1, W1s);
    hipLaunchKernelGGL(snn_main_split, dim3(1024), dim3(256), 0, stream,
                       s0g, W1s, B1, W2, B2, W3, B3, W4, B4, out);
  } else {
    hipLaunchKernelGGL(snn_fb, dim3(1024), dim3(256), 0, stream,
                       x, W1, B1, W2, B2, W3, B3, W4, B4, out);
  }
}